// Round 10
// baseline (1968.220 us; speedup 1.0000x reference)
//
#include <hip/hip_runtime.h>

typedef _Float16 hf;
typedef _Float16 hf8 __attribute__((ext_vector_type(8)));
typedef float f32x4 __attribute__((ext_vector_type(4)));

static constexpr int BATCH = 4;
static constexpr int TPTS  = 65536;
static constexpr int NPTS  = BATCH * TPTS;   // 262144
static constexpr int R3    = 32768;
static constexpr int NVOX  = BATCH * R3;     // 131072

// fragment-linear f16 weight buffers (units of hf) inside d_out scratch.
static constexpr int OFF_WPOS = 0;         // K=64(pad 60), N=256: 2048 chunks
static constexpr int OFF_W0   = 16384;     // 5 x (K=256,N=128)
static constexpr int OFF_W1   = 180224;    // 5 x (K=128,N=128)
static constexpr int OFF_WSC  = 262144;    // 5 x (K=256,N=128)
static constexpr int OFF_WC   = 425984;    // K=128,N=128
static constexpr int NCHUNKS  = 55296;

__device__ constexpr int kpat(int g, int j) { return (j & 3) + 4 * g + 16 * (j >> 2); }

#define MFMA16(a, b, c) __builtin_amdgcn_mfma_f32_16x16x32_f16((a), (b), (c), 0, 0, 0)

__device__ inline hf8 relu8(hf8 a) {
#pragma unroll
  for (int i = 0; i < 8; ++i) a[i] = (a[i] > (hf)0) ? a[i] : (hf)0;
  return a;
}
__device__ inline f32x4 splat4(float v) {
  f32x4 r; r[0] = v; r[1] = v; r[2] = v; r[3] = v; return r;
}
__device__ inline hf8 ldfrag(const hf* __restrict__ base, int kc, int nt, int NT, int lane) {
  return *(const hf8*)(base + (((size_t)(kc * NT + nt) * 64 + lane) << 3));
}

// ---------------- weight fragment prep --------------------------------------
__global__ __launch_bounds__(256) void k_prep(
    const float* __restrict__ wpos, const float* __restrict__ w0,
    const float* __restrict__ w1,  const float* __restrict__ wsc,
    const float* __restrict__ wc,  hf* __restrict__ fr)
{
  const int cid = blockIdx.x * 256 + threadIdx.x;
  if (cid >= NCHUNKS) return;
  const float* src; hf* dst; int NT, N, kmax, loc;
  if (cid < 2048) {
    src = wpos; dst = fr + OFF_WPOS; NT = 16; N = 256; kmax = 60; loc = cid;
  } else if (cid < 22528) {
    int l5 = cid - 2048; int i = l5 >> 12; loc = l5 & 4095;
    src = w0 + (size_t)i * 32768; dst = fr + OFF_W0 + (size_t)i * 32768;
    NT = 8; N = 128; kmax = 256;
  } else if (cid < 32768) {
    int l5 = cid - 22528; int i = l5 >> 11; loc = l5 & 2047;
    src = w1 + (size_t)i * 16384; dst = fr + OFF_W1 + (size_t)i * 16384;
    NT = 8; N = 128; kmax = 128;
  } else if (cid < 53248) {
    int l5 = cid - 32768; int i = l5 >> 12; loc = l5 & 4095;
    src = wsc + (size_t)i * 32768; dst = fr + OFF_WSC + (size_t)i * 32768;
    NT = 8; N = 128; kmax = 256;
  } else {
    loc = cid - 53248; src = wc; dst = fr + OFF_WC; NT = 8; N = 128; kmax = 128;
  }
  const int lane = loc & 63;
  const int rest = loc >> 6;
  const int nt = rest % NT, kc = rest / NT;
  const int g = lane >> 4;
  const int n = nt * 16 + (lane & 15);
  union { hf8 h; hf f[8]; } o;
#pragma unroll
  for (int j = 0; j < 8; ++j) {
    int k = kc * 32 + kpat(g, j);
    o.f[j] = (k < kmax) ? (hf)src[(size_t)k * N + n] : (hf)0;
  }
  *(hf8*)(dst + ((size_t)loc << 3)) = o.h;
}

// ---------------- voxel index + count (fused) --------------------------------
__global__ __launch_bounds__(256) void k_idxcnt(
    const float* __restrict__ p, int* __restrict__ idxbuf, int* __restrict__ cnt)
{
  const int t = blockIdx.x * 256 + threadIdx.x;
  const float px = p[(size_t)t * 3 + 0];
  const float py = p[(size_t)t * 3 + 1];
  const float pz = p[(size_t)t * 3 + 2];
  float nx = fminf(fmaxf(px / 1.101f + 0.5f, 0.0f), 0.999f);
  float ny = fminf(fmaxf(py / 1.101f + 0.5f, 0.0f), 0.999f);
  float nz = fminf(fmaxf(pz / 1.101f + 0.5f, 0.0f), 0.999f);
  const int iv = (int)(nx * 32.f) + 32 * (int)(ny * 32.f) + 1024 * (int)(nz * 32.f);
  idxbuf[t] = iv;
  atomicAdd(&cnt[((t >> 16) << 15) | iv], 1);
}

__global__ __launch_bounds__(256) void k_scan(
    const int* __restrict__ cnt, int* __restrict__ start, int* __restrict__ total)
{
  __shared__ int s[256];
  __shared__ int base_s;
  const int tid = threadIdx.x;
  const int v0 = blockIdx.x * 512;
  const int a = cnt[v0 + 2 * tid], b = cnt[v0 + 2 * tid + 1];
  const int sum = a + b;
  s[tid] = sum;
  __syncthreads();
  for (int off = 1; off < 256; off <<= 1) {
    int x = (tid >= off) ? s[tid - off] : 0;
    __syncthreads();
    s[tid] += x;
    __syncthreads();
  }
  if (tid == 255) base_s = atomicAdd(total, s[255]);
  __syncthreads();
  const int excl = base_s + s[tid] - sum;
  start[v0 + 2 * tid]     = excl;
  start[v0 + 2 * tid + 1] = excl + a;
}

// fill: advance start[bv] to END; record sorted slot (spos, in-place over
// idxbuf) and voxel per sorted slot (svox).
__global__ __launch_bounds__(256) void k_fill(
    int* __restrict__ idxbuf, int* __restrict__ start, int* __restrict__ svox)
{
  const int t = blockIdx.x * 256 + threadIdx.x;
  const int bv = ((t >> 16) << 15) | idxbuf[t];
  const int pos = atomicAdd(&start[bv], 1);
  svox[pos] = bv;
  idxbuf[t] = pos;     // idxbuf becomes spos
}

// -------- fused: pos-enc + fc_pos (60->256) + ResnetBlock 0 (64 pts) --------
__global__ __launch_bounds__(256, 4) void k_fused0(
    const float* __restrict__ p, const hf* __restrict__ fr,
    const float* __restrict__ bpos,
    const hf* __restrict__ w0f, const hf* __restrict__ w1f,
    const hf* __restrict__ wscf,
    const float* __restrict__ b0, const float* __restrict__ b1,
    const int* __restrict__ spos, hf* __restrict__ net)
{
  __shared__ __align__(16) hf swX[16384];   // 32 KB: enc (8KB) -> X frags; H aliases
  __shared__ int sp[64];
  const int tid = threadIdx.x;
  const int wv = tid >> 6, lane = tid & 63;
  const int r = lane & 15, g = lane >> 4;
  const int t0 = blockIdx.x * 64;

  if (tid < 64) sp[tid] = spos[t0 + tid];

  // Phase A: cooperative pos-enc (1920 tasks over 256 threads).
  if (tid < 64) {
    const int mt = tid >> 4, rr = tid & 15;
    *(unsigned long long*)(swX + (((mt * 2 + 1) * 64 + 48 + rr) << 3) + 4) = 0ull;
  }
#pragma unroll
  for (int i = 0; i < 8; ++i) {
    const int tau = tid + i * 256;
    if (tau >= 1920) break;
    const int pt = (int)(((unsigned)tau * 34953u) >> 20);   // tau/30
    const int a  = tau - pt * 30;
    const int fi = (a * 11) >> 5;                           // a/3
    const int comp = a - 3 * fi;
    const float pc = p[(size_t)(t0 + pt) * 3 + comp];
    const float ang = (float)(1 << fi) * 3.14159274101257324f * pc;
    const float sv = __sinf(ang), cv = __cosf(ang);
    const int mt = pt >> 4, rr = pt & 15;
    const int ks = 6 * fi + comp;
    {
      const int kc = ks >> 5, kk = ks & 31, gg = (kk >> 2) & 3;
      const int e = (kk & 3) + 4 * (kk >> 4);
      swX[(((mt * 2 + kc) * 64 + gg * 16 + rr) << 3) + e] = (hf)sv;
    }
    {
      const int kco = ks + 3;
      const int kc = kco >> 5, kk = kco & 31, gg = (kk >> 2) & 3;
      const int e = (kk & 3) + 4 * (kk >> 4);
      swX[(((mt * 2 + kc) * 64 + gg * 16 + rr) << 3) + e] = (hf)cv;
    }
  }
  __syncthreads();

  // fc_pos via MFMA, A-fragments from LDS
  f32x4 acc[4][4];
#pragma unroll
  for (int nf = 0; nf < 4; ++nf) {
    float bv = bpos[wv * 64 + nf * 16 + r];
#pragma unroll
    for (int mf = 0; mf < 4; ++mf) acc[mf][nf] = splat4(bv);
  }
#pragma unroll
  for (int kc = 0; kc < 2; ++kc) {
    hf8 a[4];
#pragma unroll
    for (int mf = 0; mf < 4; ++mf)
      a[mf] = *(const hf8*)(swX + (((mf * 2 + kc) * 64 + lane) << 3));
#pragma unroll
    for (int nf = 0; nf < 4; ++nf) {
      hf8 b = ldfrag(fr + OFF_WPOS, kc, wv * 4 + nf, 16, lane);
#pragma unroll
      for (int mf = 0; mf < 4; ++mf) acc[mf][nf] = MFMA16(a[mf], b, acc[mf][nf]);
    }
  }
  __syncthreads();   // enc region dead; X-store below overwrites it

  // X -> frag-linear LDS, swizzled slot
#pragma unroll
  for (int mf = 0; mf < 4; ++mf)
#pragma unroll
    for (int nf = 0; nf < 4; ++nf)
#pragma unroll
      for (int reg = 0; reg < 4; ++reg) {
        int rr = 4 * g + reg;
        int c  = wv * 64 + nf * 16 + r;
        int kc = c >> 5;
        int kk = c & 31;
        int gg = (kk >> 2) & 3;
        int e  = (kk & 3) + 4 * (kk >> 4);
        int slot = gg * 16 + ((rr + gg) & 15);
        swX[(((size_t)(mf * 8 + kc) * 64 + slot) << 3) + e] = (hf)acc[mf][nf][reg];
      }
  __syncthreads();

  const int wm = wv >> 1, wn = wv & 1;
  const int lidx = g * 16 + ((r + g) & 15);

  f32x4 h[2][4], d[2][4];
#pragma unroll
  for (int nf = 0; nf < 4; ++nf) {
    const int n = wn * 64 + nf * 16 + r;
    const float bh = b0[n], bd = b1[n];
#pragma unroll
    for (int mf = 0; mf < 2; ++mf) { h[mf][nf] = splat4(bh); d[mf][nf] = splat4(bd); }
  }
#pragma unroll 2
  for (int kc = 0; kc < 8; ++kc) {
    hf8 a[2], ar[2];
#pragma unroll
    for (int mf = 0; mf < 2; ++mf) {
      a[mf] = *(const hf8*)(swX + (((size_t)((wm * 2 + mf) * 8 + kc) * 64 + lidx) << 3));
      ar[mf] = relu8(a[mf]);
    }
#pragma unroll
    for (int nf = 0; nf < 4; ++nf) {
      hf8 bw0 = ldfrag(w0f, kc, wn * 4 + nf, 8, lane);
      hf8 bws = ldfrag(wscf, kc, wn * 4 + nf, 8, lane);
#pragma unroll
      for (int mf = 0; mf < 2; ++mf) {
        h[mf][nf] = MFMA16(ar[mf], bw0, h[mf][nf]);
        d[mf][nf] = MFMA16(a[mf],  bws, d[mf][nf]);
      }
    }
  }
  __syncthreads();

#pragma unroll
  for (int mf = 0; mf < 2; ++mf)
#pragma unroll
    for (int nf = 0; nf < 4; ++nf)
#pragma unroll
      for (int reg = 0; reg < 4; ++reg) {
        int m = wm * 32 + mf * 16 + 4 * g + reg;
        int k = wn * 64 + nf * 16 + r;
        float hv = fmaxf(h[mf][nf][reg], 0.f);
        int mt = m >> 4, rr = m & 15;
        int kc = k >> 5, kk = k & 31;
        int gg = (kk >> 2) & 3;
        int e = (kk & 3) + 4 * (kk >> 4);
        int slot = gg * 16 + ((rr + gg) & 15);
        swX[(((size_t)(mt * 4 + kc) * 64 + slot) << 3) + e] = (hf)hv;
      }
  __syncthreads();

#pragma unroll
  for (int kc = 0; kc < 4; ++kc) {
    hf8 a[2];
#pragma unroll
    for (int mf = 0; mf < 2; ++mf)
      a[mf] = *(const hf8*)(swX + (((size_t)((wm * 2 + mf) * 4 + kc) * 64 + lidx) << 3));
#pragma unroll
    for (int nf = 0; nf < 4; ++nf) {
      hf8 bw1 = ldfrag(w1f, kc, wn * 4 + nf, 8, lane);
#pragma unroll
      for (int mf = 0; mf < 2; ++mf) d[mf][nf] = MFMA16(a[mf], bw1, d[mf][nf]);
    }
  }

#pragma unroll
  for (int mf = 0; mf < 2; ++mf)
#pragma unroll
    for (int nf = 0; nf < 4; ++nf)
#pragma unroll
      for (int reg = 0; reg < 4; ++reg) {
        int m = wm * 32 + mf * 16 + 4 * g + reg;
        int n = wn * 64 + nf * 16 + r;
        net[(size_t)sp[m] * 128 + n] = (hf)d[mf][nf][reg];
      }
}

// ---- ResnetBlockFC for 128 sorted points via MFMA, 32KB LDS (4 blk/CU). ----
// X staged in two K-halves through the SAME 32KB region:
//   stage ch 0..127 -> fc0/sc kc0-3 -> walk-pool ch 128..255 -> fc0/sc kc4-7
// Pooled store packed as 2 x b64 per row (was 8 scalar b16, 8-way conflict).
// LAST=1: fc_c fused at the tail.
template <int LAST>
__global__ __launch_bounds__(256, 4) void k_res(
    const hf* __restrict__ netin, hf* __restrict__ netout,
    const int* __restrict__ svox,
    const int* __restrict__ startb, const int* __restrict__ cnt,
    const hf* __restrict__ w0f, const hf* __restrict__ w1f,
    const hf* __restrict__ wscf,
    const float* __restrict__ b0, const float* __restrict__ b1,
    const hf* __restrict__ wcf, const float* __restrict__ bc)
{
  __shared__ __align__(16) hf swX[16384];   // 32 KB, reused 3x (Xlo/Xhi/H)
  const int tid = threadIdx.x;
  const int wv = tid >> 6, lane = tid & 63;
  const int r = lane & 15, g = lane >> 4;
  const int wm = wv >> 1, wn = wv & 1;
  const int t0 = blockIdx.x * 128;
  const int lidx = g * 16 + ((r + g) & 15);

  // phase 1: stage lower half (net channels 0..127), frag-linear [mt][kc:0..3]
  for (int cc = tid; cc < 2048; cc += 256) {
    const int cl = cc & 63;
    const int kc = (cc >> 6) & 3;      // 0..3
    const int mt = cc >> 8;            // 0..7
    const int rr = cl & 15, gg = cl >> 4;
    const int t = t0 + mt * 16 + rr;
    const int c1 = kc * 32 + 4 * gg;
    union { hf8 h; uint2 u2[2]; } x;
    const hf* srcp = netin + (size_t)t * 128 + c1;
    x.u2[0] = *(const uint2*)(srcp);
    x.u2[1] = *(const uint2*)(srcp + 16);
    const int slot = gg * 16 + ((rr + gg) & 15);
    *(hf8*)(swX + (((size_t)((mt * 4 + kc) * 64 + slot)) << 3)) = x.h;
  }

  f32x4 h[4][4], d[4][4];
#pragma unroll
  for (int nf = 0; nf < 4; ++nf) {
    const int n = wn * 64 + nf * 16 + r;
    const float bh = b0[n], bd = b1[n];
#pragma unroll
    for (int mf = 0; mf < 4; ++mf) { h[mf][nf] = splat4(bh); d[mf][nf] = splat4(bd); }
  }
  __syncthreads();

  // phase 2: fc0/sc over kc = 0..3
#pragma unroll 2
  for (int kc = 0; kc < 4; ++kc) {
    hf8 a[4], ar[4];
#pragma unroll
    for (int mf = 0; mf < 4; ++mf) {
      a[mf] = *(const hf8*)(swX + (((size_t)((wm * 4 + mf) * 4 + kc) * 64 + lidx) << 3));
      ar[mf] = relu8(a[mf]);
    }
#pragma unroll
    for (int nf = 0; nf < 4; ++nf) {
      hf8 bw0 = ldfrag(w0f, kc, wn * 4 + nf, 8, lane);
      hf8 bws = ldfrag(wscf, kc, wn * 4 + nf, 8, lane);
#pragma unroll
      for (int mf = 0; mf < 4; ++mf) {
        h[mf][nf] = MFMA16(ar[mf], bw0, h[mf][nf]);
        d[mf][nf] = MFMA16(a[mf],  bws, d[mf][nf]);
      }
    }
  }
  __syncthreads();

  // phase 3: pooled half via CSR segment walks -> same 32KB region [mt][kcp]
  {
    const int grp = tid >> 4, q = tid & 15;
    const int q3 = q & 3;
    const int kcp = q >> 2;            // 0..3
    const int hi = q3 >> 1;            // e-base/4
    const int rbase = t0 + grp * 8;
    int vprev = -1;
    float m[8];
#pragma unroll
    for (int e = 0; e < 8; ++e) m[e] = -1e30f;
    for (int rloc = 0; rloc < 8; ++rloc) {
      const int t = rbase + rloc;
      const int v = svox[t];
      if (v != vprev) {
        vprev = v;
        const int end = startb[v];
        const int beg = end - cnt[v];
#pragma unroll
        for (int e = 0; e < 8; ++e) m[e] = -1e30f;
        for (int j = beg; j < end; ++j) {
          union { uint4 u; hf hh[8]; } x;
          x.u = *(const uint4*)(netin + (size_t)j * 128 + 8 * q);
#pragma unroll
          for (int e = 0; e < 8; ++e) m[e] = fmaxf(m[e], (float)x.hh[e]);
        }
      }
      const int mt = (t - t0) >> 4, rr = (t - t0) & 15;
#pragma unroll
      for (int j = 0; j < 2; ++j) {
        const int gg = (2 * q3 + j) & 3;
        const int slot = gg * 16 + ((rr + gg) & 15);
        union { unsigned long long u; hf f[4]; } pk;
#pragma unroll
        for (int ii = 0; ii < 4; ++ii) pk.f[ii] = (hf)m[4 * j + ii];
        *(unsigned long long*)(swX + (((size_t)((mt * 4 + kcp) * 64 + slot)) << 3) + 4 * hi) = pk.u;
      }
    }
  }
  __syncthreads();

  // phase 4: fc0/sc over kc = 4..7 (region holds kcp = kc-4)
#pragma unroll 2
  for (int kc = 4; kc < 8; ++kc) {
    hf8 a[4], ar[4];
#pragma unroll
    for (int mf = 0; mf < 4; ++mf) {
      a[mf] = *(const hf8*)(swX + (((size_t)((wm * 4 + mf) * 4 + (kc - 4)) * 64 + lidx) << 3));
      ar[mf] = relu8(a[mf]);
    }
#pragma unroll
    for (int nf = 0; nf < 4; ++nf) {
      hf8 bw0 = ldfrag(w0f, kc, wn * 4 + nf, 8, lane);
      hf8 bws = ldfrag(wscf, kc, wn * 4 + nf, 8, lane);
#pragma unroll
      for (int mf = 0; mf < 4; ++mf) {
        h[mf][nf] = MFMA16(ar[mf], bw0, h[mf][nf]);
        d[mf][nf] = MFMA16(a[mf],  bws, d[mf][nf]);
      }
    }
  }
  __syncthreads();

  // phase 5: H = relu(h) -> swX (32KB exact), swizzled (2-way banks, free)
#pragma unroll
  for (int mf = 0; mf < 4; ++mf)
#pragma unroll
    for (int nf = 0; nf < 4; ++nf)
#pragma unroll
      for (int reg = 0; reg < 4; ++reg) {
        int m = wm * 64 + mf * 16 + 4 * g + reg;
        int k = wn * 64 + nf * 16 + r;
        float hv = fmaxf(h[mf][nf][reg], 0.f);
        int mt = m >> 4, rr = m & 15;
        int kc = k >> 5, kk = k & 31;
        int gg = (kk >> 2) & 3;
        int e = (kk & 3) + 4 * (kk >> 4);
        int slot = gg * 16 + ((rr + gg) & 15);
        swX[(((size_t)(mt * 4 + kc) * 64 + slot) << 3) + e] = (hf)hv;
      }
  __syncthreads();

  // phase 6: fc1
#pragma unroll
  for (int kc = 0; kc < 4; ++kc) {
    hf8 a[4];
#pragma unroll
    for (int mf = 0; mf < 4; ++mf)
      a[mf] = *(const hf8*)(swX + (((size_t)((wm * 4 + mf) * 4 + kc) * 64 + lidx) << 3));
#pragma unroll
    for (int nf = 0; nf < 4; ++nf) {
      hf8 bw1 = ldfrag(w1f, kc, wn * 4 + nf, 8, lane);
#pragma unroll
      for (int mf = 0; mf < 4; ++mf) d[mf][nf] = MFMA16(a[mf], bw1, d[mf][nf]);
    }
  }

  if (LAST) {
    __syncthreads();
#pragma unroll
    for (int mf = 0; mf < 4; ++mf)
#pragma unroll
      for (int nf = 0; nf < 4; ++nf)
#pragma unroll
        for (int reg = 0; reg < 4; ++reg) {
          int m = wm * 64 + mf * 16 + 4 * g + reg;
          int k = wn * 64 + nf * 16 + r;
          int mt = m >> 4, rr = m & 15;
          int kc = k >> 5, kk = k & 31;
          int gg = (kk >> 2) & 3;
          int e = (kk & 3) + 4 * (kk >> 4);
          int slot = gg * 16 + ((rr + gg) & 15);
          swX[(((size_t)(mt * 4 + kc) * 64 + slot) << 3) + e] = (hf)d[mf][nf][reg];
        }
    __syncthreads();

    f32x4 c2[4][4];
#pragma unroll
    for (int nf = 0; nf < 4; ++nf) {
      float bv = bc[wn * 64 + nf * 16 + r];
#pragma unroll
      for (int mf = 0; mf < 4; ++mf) c2[mf][nf] = splat4(bv);
    }
#pragma unroll
    for (int kc = 0; kc < 4; ++kc) {
      hf8 a[4];
#pragma unroll
      for (int mf = 0; mf < 4; ++mf)
        a[mf] = *(const hf8*)(swX + (((size_t)((wm * 4 + mf) * 4 + kc) * 64 + lidx) << 3));
#pragma unroll
      for (int nf = 0; nf < 4; ++nf) {
        hf8 bw = ldfrag(wcf, kc, wn * 4 + nf, 8, lane);
#pragma unroll
        for (int mf = 0; mf < 4; ++mf) c2[mf][nf] = MFMA16(a[mf], bw, c2[mf][nf]);
      }
    }
#pragma unroll
    for (int mf = 0; mf < 4; ++mf)
#pragma unroll
      for (int nf = 0; nf < 4; ++nf)
#pragma unroll
        for (int reg = 0; reg < 4; ++reg) {
          int m = wm * 64 + mf * 16 + 4 * g + reg;
          int n = wn * 64 + nf * 16 + r;
          netout[(size_t)(t0 + m) * 128 + n] = (hf)c2[mf][nf][reg];
        }
  } else {
#pragma unroll
    for (int mf = 0; mf < 4; ++mf)
#pragma unroll
      for (int nf = 0; nf < 4; ++nf)
#pragma unroll
        for (int reg = 0; reg < 4; ++reg) {
          int m = wm * 64 + mf * 16 + 4 * g + reg;
          int n = wn * 64 + nf * 16 + r;
          netout[(size_t)(t0 + m) * 128 + n] = (hf)d[mf][nf][reg];
        }
  }
}

// ---------------- streaming gather-mean + transpose -------------------------
__global__ __launch_bounds__(256) void k_write(
    const hf* __restrict__ cbuf, const int* __restrict__ start,
    const int* __restrict__ cnt, float* __restrict__ out)
{
  __shared__ float tile[128 * 65];
  const int tid = threadIdx.x;
  const int grp = tid >> 4, q = tid & 15;
  const int g0 = blockIdx.x * 64;        // voxel base, (b<<15)|v0
  for (int vl = grp; vl < 64; vl += 16) {
    const int bv = g0 + vl;
    const int n = cnt[bv];
    const int end = start[bv], beg = end - n;
    float s[8] = {0, 0, 0, 0, 0, 0, 0, 0};
    for (int i = beg; i < end; ++i) {
      union { uint4 u; hf h[8]; } x;
      x.u = *(const uint4*)(cbuf + (size_t)i * 128 + 8 * q);
#pragma unroll
      for (int e = 0; e < 8; ++e) s[e] += (float)x.h[e];
    }
    const float inv = 1.0f / fmaxf((float)n, 1.0f);
#pragma unroll
    for (int e = 0; e < 8; ++e) tile[(8 * q + e) * 65 + vl] = s[e] * inv;
  }
  __syncthreads();
  const int b = g0 >> 15, v0 = g0 & 32767;
  for (int i = tid; i < 8192; i += 256) {
    const int c = i >> 6, vl = i & 63;
    out[(((size_t)(b * 128 + c)) << 15) + v0 + vl] = tile[c * 65 + vl];
  }
}

extern "C" void kernel_launch(void* const* d_in, const int* in_sizes, int n_in,
                              void* d_out, int out_size, void* d_ws, size_t ws_size,
                              hipStream_t stream)
{
  const float* p    = (const float*)d_in[0];
  const float* wpos = (const float*)d_in[1];
  const float* bpos = (const float*)d_in[2];
  const float* w0   = (const float*)d_in[3];
  const float* b0   = (const float*)d_in[4];
  const float* w1   = (const float*)d_in[5];
  const float* b1   = (const float*)d_in[6];
  const float* wsc  = (const float*)d_in[7];
  const float* wc   = (const float*)d_in[8];
  const float* bc   = (const float*)d_in[9];

  char* ws = (char*)d_ws;
  hf*  fr  = (hf*)d_out;  // weight frags; d_out fully overwritten by k_write

  // Layout: idx 1M | netA 64M | netB 64M | cnt .5M | tot | start .5M | svox 1M
  int* idxbuf = (int*)ws;
  hf*  netA   = (hf*)(ws + ((size_t)1u << 20));
  hf*  netB   = (hf*)(ws + ((size_t)65u << 20));
  int* cnt32  = (int*)(ws + ((size_t)129u << 20));
  int* startb = (int*)(ws + ((size_t)129u << 20) + 0x80400);
  int* svox   = (int*)(ws + ((size_t)129u << 20) + 0x100400);

  k_prep<<<216, 256, 0, stream>>>(wpos, w0, w1, wsc, wc, fr);

  hipMemsetAsync(cnt32, 0, 0x80000 + 0x400, stream);  // cnt + total
  k_idxcnt<<<NPTS / 256, 256, 0, stream>>>(p, idxbuf, cnt32);
  k_scan<<<NVOX / 512, 256, 0, stream>>>(cnt32, startb,
                                         (int*)(ws + ((size_t)129u << 20) + 0x80000));
  k_fill<<<NPTS / 256, 256, 0, stream>>>(idxbuf, startb, svox);

  k_fused0<<<NPTS / 64, 256, 0, stream>>>(p, fr, bpos,
      fr + OFF_W0, fr + OFF_W1, fr + OFF_WSC, b0, b1, idxbuf, netA);

  hf* bufs[2] = { netA, netB };
  for (int i = 1; i < 4; ++i) {
    k_res<0><<<NPTS / 128, 256, 0, stream>>>(
        bufs[(i + 1) & 1], bufs[i & 1], svox, startb, cnt32,
        fr + OFF_W0 + (size_t)i * 32768, fr + OFF_W1 + (size_t)i * 16384,
        fr + OFF_WSC + (size_t)i * 32768, b0 + i * 128, b1 + i * 128,
        nullptr, nullptr);
  }
  // i=4: B -> A (LAST, fc_c fused)
  k_res<1><<<NPTS / 128, 256, 0, stream>>>(
      netB, netA, svox, startb, cnt32,
      fr + OFF_W0 + (size_t)4 * 32768, fr + OFF_W1 + (size_t)4 * 16384,
      fr + OFF_WSC + (size_t)4 * 32768, b0 + 4 * 128, b1 + 4 * 128,
      fr + OFF_WC, bc);

  k_write<<<NVOX / 64, 256, 0, stream>>>(netA, startb, cnt32, (float*)d_out);
}

// Round 11
// 576.908 us; speedup vs baseline: 3.4117x; 3.4117x over previous
//
#include <hip/hip_runtime.h>

typedef _Float16 hf;
typedef _Float16 hf8 __attribute__((ext_vector_type(8)));
typedef float f32x4 __attribute__((ext_vector_type(4)));

static constexpr int BATCH = 4;
static constexpr int TPTS  = 65536;
static constexpr int NPTS  = BATCH * TPTS;   // 262144
static constexpr int R3    = 32768;
static constexpr int NVOX  = BATCH * R3;     // 131072

// fragment-linear f16 weight buffers (units of hf) inside d_out scratch.
static constexpr int OFF_WPOS = 0;         // K=64(pad 60), N=256: 2048 chunks
static constexpr int OFF_W0   = 16384;     // 5 x (K=256,N=128)
static constexpr int OFF_W1   = 180224;    // 5 x (K=128,N=128)
static constexpr int OFF_WSC  = 262144;    // 5 x (K=256,N=128)
static constexpr int OFF_WC   = 425984;    // K=128,N=128
static constexpr int NCHUNKS  = 55296;

__device__ constexpr int kpat(int g, int j) { return (j & 3) + 4 * g + 16 * (j >> 2); }

#define MFMA16(a, b, c) __builtin_amdgcn_mfma_f32_16x16x32_f16((a), (b), (c), 0, 0, 0)

__device__ inline hf8 relu8(hf8 a) {
#pragma unroll
  for (int i = 0; i < 8; ++i) a[i] = (a[i] > (hf)0) ? a[i] : (hf)0;
  return a;
}
__device__ inline f32x4 splat4(float v) {
  f32x4 r; r[0] = v; r[1] = v; r[2] = v; r[3] = v; return r;
}
__device__ inline hf8 ldfrag(const hf* __restrict__ base, int kc, int nt, int NT, int lane) {
  return *(const hf8*)(base + (((size_t)(kc * NT + nt) * 64 + lane) << 3));
}

// ---------------- weight fragment prep --------------------------------------
__global__ __launch_bounds__(256) void k_prep(
    const float* __restrict__ wpos, const float* __restrict__ w0,
    const float* __restrict__ w1,  const float* __restrict__ wsc,
    const float* __restrict__ wc,  hf* __restrict__ fr)
{
  const int cid = blockIdx.x * 256 + threadIdx.x;
  if (cid >= NCHUNKS) return;
  const float* src; hf* dst; int NT, N, kmax, loc;
  if (cid < 2048) {
    src = wpos; dst = fr + OFF_WPOS; NT = 16; N = 256; kmax = 60; loc = cid;
  } else if (cid < 22528) {
    int l5 = cid - 2048; int i = l5 >> 12; loc = l5 & 4095;
    src = w0 + (size_t)i * 32768; dst = fr + OFF_W0 + (size_t)i * 32768;
    NT = 8; N = 128; kmax = 256;
  } else if (cid < 32768) {
    int l5 = cid - 22528; int i = l5 >> 11; loc = l5 & 2047;
    src = w1 + (size_t)i * 16384; dst = fr + OFF_W1 + (size_t)i * 16384;
    NT = 8; N = 128; kmax = 128;
  } else if (cid < 53248) {
    int l5 = cid - 32768; int i = l5 >> 12; loc = l5 & 4095;
    src = wsc + (size_t)i * 32768; dst = fr + OFF_WSC + (size_t)i * 32768;
    NT = 8; N = 128; kmax = 256;
  } else {
    loc = cid - 53248; src = wc; dst = fr + OFF_WC; NT = 8; N = 128; kmax = 128;
  }
  const int lane = loc & 63;
  const int rest = loc >> 6;
  const int nt = rest % NT, kc = rest / NT;
  const int g = lane >> 4;
  const int n = nt * 16 + (lane & 15);
  union { hf8 h; hf f[8]; } o;
#pragma unroll
  for (int j = 0; j < 8; ++j) {
    int k = kc * 32 + kpat(g, j);
    o.f[j] = (k < kmax) ? (hf)src[(size_t)k * N + n] : (hf)0;
  }
  *(hf8*)(dst + ((size_t)loc << 3)) = o.h;
}

// ---------------- voxel index + count (fused) --------------------------------
__global__ __launch_bounds__(256) void k_idxcnt(
    const float* __restrict__ p, int* __restrict__ idxbuf, int* __restrict__ cnt)
{
  const int t = blockIdx.x * 256 + threadIdx.x;
  const float px = p[(size_t)t * 3 + 0];
  const float py = p[(size_t)t * 3 + 1];
  const float pz = p[(size_t)t * 3 + 2];
  float nx = fminf(fmaxf(px / 1.101f + 0.5f, 0.0f), 0.999f);
  float ny = fminf(fmaxf(py / 1.101f + 0.5f, 0.0f), 0.999f);
  float nz = fminf(fmaxf(pz / 1.101f + 0.5f, 0.0f), 0.999f);
  const int iv = (int)(nx * 32.f) + 32 * (int)(ny * 32.f) + 1024 * (int)(nz * 32.f);
  idxbuf[t] = iv;
  atomicAdd(&cnt[((t >> 16) << 15) | iv], 1);
}

__global__ __launch_bounds__(256) void k_scan(
    const int* __restrict__ cnt, int* __restrict__ start, int* __restrict__ total)
{
  __shared__ int s[256];
  __shared__ int base_s;
  const int tid = threadIdx.x;
  const int v0 = blockIdx.x * 512;
  const int a = cnt[v0 + 2 * tid], b = cnt[v0 + 2 * tid + 1];
  const int sum = a + b;
  s[tid] = sum;
  __syncthreads();
  for (int off = 1; off < 256; off <<= 1) {
    int x = (tid >= off) ? s[tid - off] : 0;
    __syncthreads();
    s[tid] += x;
    __syncthreads();
  }
  if (tid == 255) base_s = atomicAdd(total, s[255]);
  __syncthreads();
  const int excl = base_s + s[tid] - sum;
  start[v0 + 2 * tid]     = excl;
  start[v0 + 2 * tid + 1] = excl + a;
}

// fill: advance start[bv] to END; record sorted slot (spos, in-place over
// idxbuf) and voxel per sorted slot (svox).
__global__ __launch_bounds__(256) void k_fill(
    int* __restrict__ idxbuf, int* __restrict__ start, int* __restrict__ svox)
{
  const int t = blockIdx.x * 256 + threadIdx.x;
  const int bv = ((t >> 16) << 15) | idxbuf[t];
  const int pos = atomicAdd(&start[bv], 1);
  svox[pos] = bv;
  idxbuf[t] = pos;     // idxbuf becomes spos
}

// -------- fused: pos-enc + fc_pos (60->256) + ResnetBlock 0 (64 pts) --------
__global__ __launch_bounds__(256, 4) void k_fused0(
    const float* __restrict__ p, const hf* __restrict__ fr,
    const float* __restrict__ bpos,
    const hf* __restrict__ w0f, const hf* __restrict__ w1f,
    const hf* __restrict__ wscf,
    const float* __restrict__ b0, const float* __restrict__ b1,
    const int* __restrict__ spos, hf* __restrict__ net)
{
  __shared__ __align__(16) hf swX[16384];   // 32 KB: enc (8KB) -> X frags; H aliases
  __shared__ int sp[64];
  const int tid = threadIdx.x;
  const int wv = tid >> 6, lane = tid & 63;
  const int r = lane & 15, g = lane >> 4;
  const int t0 = blockIdx.x * 64;

  if (tid < 64) sp[tid] = spos[t0 + tid];

  // Phase A: cooperative pos-enc (1920 tasks over 256 threads).
  if (tid < 64) {
    const int mt = tid >> 4, rr = tid & 15;
    *(unsigned long long*)(swX + (((mt * 2 + 1) * 64 + 48 + rr) << 3) + 4) = 0ull;
  }
#pragma unroll
  for (int i = 0; i < 8; ++i) {
    const int tau = tid + i * 256;
    if (tau >= 1920) break;
    const int pt = (int)(((unsigned)tau * 34953u) >> 20);   // tau/30
    const int a  = tau - pt * 30;
    const int fi = (a * 11) >> 5;                           // a/3
    const int comp = a - 3 * fi;
    const float pc = p[(size_t)(t0 + pt) * 3 + comp];
    const float ang = (float)(1 << fi) * 3.14159274101257324f * pc;
    const float sv = __sinf(ang), cv = __cosf(ang);
    const int mt = pt >> 4, rr = pt & 15;
    const int ks = 6 * fi + comp;
    {
      const int kc = ks >> 5, kk = ks & 31, gg = (kk >> 2) & 3;
      const int e = (kk & 3) + 4 * (kk >> 4);
      swX[(((mt * 2 + kc) * 64 + gg * 16 + rr) << 3) + e] = (hf)sv;
    }
    {
      const int kco = ks + 3;
      const int kc = kco >> 5, kk = kco & 31, gg = (kk >> 2) & 3;
      const int e = (kk & 3) + 4 * (kk >> 4);
      swX[(((mt * 2 + kc) * 64 + gg * 16 + rr) << 3) + e] = (hf)cv;
    }
  }
  __syncthreads();

  // fc_pos via MFMA, A-fragments from LDS
  f32x4 acc[4][4];
#pragma unroll
  for (int nf = 0; nf < 4; ++nf) {
    float bv = bpos[wv * 64 + nf * 16 + r];
#pragma unroll
    for (int mf = 0; mf < 4; ++mf) acc[mf][nf] = splat4(bv);
  }
#pragma unroll
  for (int kc = 0; kc < 2; ++kc) {
    hf8 a[4];
#pragma unroll
    for (int mf = 0; mf < 4; ++mf)
      a[mf] = *(const hf8*)(swX + (((mf * 2 + kc) * 64 + lane) << 3));
#pragma unroll
    for (int nf = 0; nf < 4; ++nf) {
      hf8 b = ldfrag(fr + OFF_WPOS, kc, wv * 4 + nf, 16, lane);
#pragma unroll
      for (int mf = 0; mf < 4; ++mf) acc[mf][nf] = MFMA16(a[mf], b, acc[mf][nf]);
    }
  }
  __syncthreads();   // enc region dead; X-store below overwrites it

  // X -> frag-linear LDS, swizzled slot
#pragma unroll
  for (int mf = 0; mf < 4; ++mf)
#pragma unroll
    for (int nf = 0; nf < 4; ++nf)
#pragma unroll
      for (int reg = 0; reg < 4; ++reg) {
        int rr = 4 * g + reg;
        int c  = wv * 64 + nf * 16 + r;
        int kc = c >> 5;
        int kk = c & 31;
        int gg = (kk >> 2) & 3;
        int e  = (kk & 3) + 4 * (kk >> 4);
        int slot = gg * 16 + ((rr + gg) & 15);
        swX[(((size_t)(mf * 8 + kc) * 64 + slot) << 3) + e] = (hf)acc[mf][nf][reg];
      }
  __syncthreads();

  const int wm = wv >> 1, wn = wv & 1;
  const int lidx = g * 16 + ((r + g) & 15);

  f32x4 h[2][4], d[2][4];
#pragma unroll
  for (int nf = 0; nf < 4; ++nf) {
    const int n = wn * 64 + nf * 16 + r;
    const float bh = b0[n], bd = b1[n];
#pragma unroll
    for (int mf = 0; mf < 2; ++mf) { h[mf][nf] = splat4(bh); d[mf][nf] = splat4(bd); }
  }
#pragma unroll 2
  for (int kc = 0; kc < 8; ++kc) {
    hf8 a[2], ar[2];
#pragma unroll
    for (int mf = 0; mf < 2; ++mf) {
      a[mf] = *(const hf8*)(swX + (((size_t)((wm * 2 + mf) * 8 + kc) * 64 + lidx) << 3));
      ar[mf] = relu8(a[mf]);
    }
#pragma unroll
    for (int nf = 0; nf < 4; ++nf) {
      hf8 bw0 = ldfrag(w0f, kc, wn * 4 + nf, 8, lane);
      hf8 bws = ldfrag(wscf, kc, wn * 4 + nf, 8, lane);
#pragma unroll
      for (int mf = 0; mf < 2; ++mf) {
        h[mf][nf] = MFMA16(ar[mf], bw0, h[mf][nf]);
        d[mf][nf] = MFMA16(a[mf],  bws, d[mf][nf]);
      }
    }
  }
  __syncthreads();

#pragma unroll
  for (int mf = 0; mf < 2; ++mf)
#pragma unroll
    for (int nf = 0; nf < 4; ++nf)
#pragma unroll
      for (int reg = 0; reg < 4; ++reg) {
        int m = wm * 32 + mf * 16 + 4 * g + reg;
        int k = wn * 64 + nf * 16 + r;
        float hv = fmaxf(h[mf][nf][reg], 0.f);
        int mt = m >> 4, rr = m & 15;
        int kc = k >> 5, kk = k & 31;
        int gg = (kk >> 2) & 3;
        int e = (kk & 3) + 4 * (kk >> 4);
        int slot = gg * 16 + ((rr + gg) & 15);
        swX[(((size_t)(mt * 4 + kc) * 64 + slot) << 3) + e] = (hf)hv;
      }
  __syncthreads();

#pragma unroll
  for (int kc = 0; kc < 4; ++kc) {
    hf8 a[2];
#pragma unroll
    for (int mf = 0; mf < 2; ++mf)
      a[mf] = *(const hf8*)(swX + (((size_t)((wm * 2 + mf) * 4 + kc) * 64 + lidx) << 3));
#pragma unroll
    for (int nf = 0; nf < 4; ++nf) {
      hf8 bw1 = ldfrag(w1f, kc, wn * 4 + nf, 8, lane);
#pragma unroll
      for (int mf = 0; mf < 2; ++mf) d[mf][nf] = MFMA16(a[mf], bw1, d[mf][nf]);
    }
  }

#pragma unroll
  for (int mf = 0; mf < 2; ++mf)
#pragma unroll
    for (int nf = 0; nf < 4; ++nf)
#pragma unroll
      for (int reg = 0; reg < 4; ++reg) {
        int m = wm * 32 + mf * 16 + 4 * g + reg;
        int n = wn * 64 + nf * 16 + r;
        net[(size_t)sp[m] * 128 + n] = (hf)d[mf][nf][reg];
      }
}

// ---- ResnetBlockFC for 128 sorted points via MFMA (64KB LDS, 2 blk/CU). ----
// Pooled X-half computed in-kernel via CSR segment walks over netin
// (ping-pong netin != netout). Pooled LDS store packed as 2 x b64 per row
// (same bytes as round-9 scalar stores; ~4-way banks on 4x fewer stores).
// LAST=1: fc_c fused at the tail.
template <int LAST>
__global__ __launch_bounds__(256, 2) void k_res(
    const hf* __restrict__ netin, hf* __restrict__ netout,
    const int* __restrict__ svox,
    const int* __restrict__ startb, const int* __restrict__ cnt,
    const hf* __restrict__ w0f, const hf* __restrict__ w1f,
    const hf* __restrict__ wscf,
    const float* __restrict__ b0, const float* __restrict__ b1,
    const hf* __restrict__ wcf, const float* __restrict__ bc)
{
  __shared__ __align__(16) hf swX[32768];   // 64 KB: X frags; H (32KB) aliases
  const int tid = threadIdx.x;
  const int wv = tid >> 6, lane = tid & 63;
  const int r = lane & 15, g = lane >> 4;
  const int wm = wv >> 1, wn = wv & 1;
  const int t0 = blockIdx.x * 128;
  const int lidx = g * 16 + ((r + g) & 15);

  // lower half: net channels 0-127 of own rows
  for (int cc = tid; cc < 2048; cc += 256) {
    const int cl = cc & 63;
    const int kc = (cc >> 6) & 3;      // 0..3
    const int mt = cc >> 8;            // 0..7
    const int rr = cl & 15, gg = cl >> 4;
    const int t = t0 + mt * 16 + rr;
    const int c1 = kc * 32 + 4 * gg;
    union { hf8 h; uint2 u2[2]; } x;
    const hf* srcp = netin + (size_t)t * 128 + c1;
    x.u2[0] = *(const uint2*)(srcp);
    x.u2[1] = *(const uint2*)(srcp + 16);
    const int slot = gg * 16 + ((rr + gg) & 15);
    *(hf8*)(swX + (((size_t)((mt * 8 + kc) * 64 + slot)) << 3)) = x.h;
  }
  // upper half: pooled values via CSR segment walks (group = 8 rows x 8 ch),
  // packed 2 x b64 stores per row.
  {
    const int grp = tid >> 4, q = tid & 15;
    const int q3 = q & 3;
    const int kcf = 4 + (q >> 2);      // 4..7
    const int hi = q3 >> 1;            // e-offset / 4
    const int rbase = t0 + grp * 8;
    int vprev = -1;
    float m[8];
#pragma unroll
    for (int e = 0; e < 8; ++e) m[e] = -1e30f;
    for (int rloc = 0; rloc < 8; ++rloc) {
      const int t = rbase + rloc;
      const int v = svox[t];
      if (v != vprev) {
        vprev = v;
        const int end = startb[v];
        const int beg = end - cnt[v];
#pragma unroll
        for (int e = 0; e < 8; ++e) m[e] = -1e30f;
        for (int j = beg; j < end; ++j) {
          union { uint4 u; hf hh[8]; } x;
          x.u = *(const uint4*)(netin + (size_t)j * 128 + 8 * q);
#pragma unroll
          for (int e = 0; e < 8; ++e) m[e] = fmaxf(m[e], (float)x.hh[e]);
        }
      }
      const int mt = (t - t0) >> 4, rr = (t - t0) & 15;
#pragma unroll
      for (int j = 0; j < 2; ++j) {
        const int gg = (2 * q3 + j) & 3;
        const int slot = gg * 16 + ((rr + gg) & 15);
        union { unsigned long long u; hf f[4]; } pk;
#pragma unroll
        for (int ii = 0; ii < 4; ++ii) pk.f[ii] = (hf)m[4 * j + ii];
        *(unsigned long long*)(swX + (((size_t)((mt * 8 + kcf) * 64 + slot)) << 3) + 4 * hi) = pk.u;
      }
    }
  }
  __syncthreads();

  f32x4 h[4][4], d[4][4];
#pragma unroll
  for (int nf = 0; nf < 4; ++nf) {
    const int n = wn * 64 + nf * 16 + r;
    const float bh = b0[n], bd = b1[n];
#pragma unroll
    for (int mf = 0; mf < 4; ++mf) { h[mf][nf] = splat4(bh); d[mf][nf] = splat4(bd); }
  }
#pragma unroll 2
  for (int kc = 0; kc < 8; ++kc) {
    hf8 a[4], ar[4];
#pragma unroll
    for (int mf = 0; mf < 4; ++mf) {
      a[mf] = *(const hf8*)(swX + (((size_t)((wm * 4 + mf) * 8 + kc) * 64 + lidx) << 3));
      ar[mf] = relu8(a[mf]);
    }
#pragma unroll
    for (int nf = 0; nf < 4; ++nf) {
      hf8 bw0 = ldfrag(w0f, kc, wn * 4 + nf, 8, lane);
      hf8 bws = ldfrag(wscf, kc, wn * 4 + nf, 8, lane);
#pragma unroll
      for (int mf = 0; mf < 4; ++mf) {
        h[mf][nf] = MFMA16(ar[mf], bw0, h[mf][nf]);
        d[mf][nf] = MFMA16(a[mf],  bws, d[mf][nf]);
      }
    }
  }
  __syncthreads();

  // H = relu(h) -> swX[0..16384), swizzled
#pragma unroll
  for (int mf = 0; mf < 4; ++mf)
#pragma unroll
    for (int nf = 0; nf < 4; ++nf)
#pragma unroll
      for (int reg = 0; reg < 4; ++reg) {
        int m = wm * 64 + mf * 16 + 4 * g + reg;
        int k = wn * 64 + nf * 16 + r;
        float hv = fmaxf(h[mf][nf][reg], 0.f);
        int mt = m >> 4, rr = m & 15;
        int kc = k >> 5, kk = k & 31;
        int gg = (kk >> 2) & 3;
        int e = (kk & 3) + 4 * (kk >> 4);
        int slot = gg * 16 + ((rr + gg) & 15);
        swX[(((size_t)(mt * 4 + kc) * 64 + slot) << 3) + e] = (hf)hv;
      }
  __syncthreads();

#pragma unroll
  for (int kc = 0; kc < 4; ++kc) {
    hf8 a[4];
#pragma unroll
    for (int mf = 0; mf < 4; ++mf)
      a[mf] = *(const hf8*)(swX + (((size_t)((wm * 4 + mf) * 4 + kc) * 64 + lidx) << 3));
#pragma unroll
    for (int nf = 0; nf < 4; ++nf) {
      hf8 bw1 = ldfrag(w1f, kc, wn * 4 + nf, 8, lane);
#pragma unroll
      for (int mf = 0; mf < 4; ++mf) d[mf][nf] = MFMA16(a[mf], bw1, d[mf][nf]);
    }
  }

  if (LAST) {
    __syncthreads();
#pragma unroll
    for (int mf = 0; mf < 4; ++mf)
#pragma unroll
      for (int nf = 0; nf < 4; ++nf)
#pragma unroll
        for (int reg = 0; reg < 4; ++reg) {
          int m = wm * 64 + mf * 16 + 4 * g + reg;
          int k = wn * 64 + nf * 16 + r;
          int mt = m >> 4, rr = m & 15;
          int kc = k >> 5, kk = k & 31;
          int gg = (kk >> 2) & 3;
          int e = (kk & 3) + 4 * (kk >> 4);
          int slot = gg * 16 + ((rr + gg) & 15);
          swX[(((size_t)(mt * 4 + kc) * 64 + slot) << 3) + e] = (hf)d[mf][nf][reg];
        }
    __syncthreads();

    f32x4 c2[4][4];
#pragma unroll
    for (int nf = 0; nf < 4; ++nf) {
      float bv = bc[wn * 64 + nf * 16 + r];
#pragma unroll
      for (int mf = 0; mf < 4; ++mf) c2[mf][nf] = splat4(bv);
    }
#pragma unroll
    for (int kc = 0; kc < 4; ++kc) {
      hf8 a[4];
#pragma unroll
      for (int mf = 0; mf < 4; ++mf)
        a[mf] = *(const hf8*)(swX + (((size_t)((wm * 4 + mf) * 4 + kc) * 64 + lidx) << 3));
#pragma unroll
      for (int nf = 0; nf < 4; ++nf) {
        hf8 bw = ldfrag(wcf, kc, wn * 4 + nf, 8, lane);
#pragma unroll
        for (int mf = 0; mf < 4; ++mf) c2[mf][nf] = MFMA16(a[mf], bw, c2[mf][nf]);
      }
    }
#pragma unroll
    for (int mf = 0; mf < 4; ++mf)
#pragma unroll
      for (int nf = 0; nf < 4; ++nf)
#pragma unroll
        for (int reg = 0; reg < 4; ++reg) {
          int m = wm * 64 + mf * 16 + 4 * g + reg;
          int n = wn * 64 + nf * 16 + r;
          netout[(size_t)(t0 + m) * 128 + n] = (hf)c2[mf][nf][reg];
        }
  } else {
#pragma unroll
    for (int mf = 0; mf < 4; ++mf)
#pragma unroll
      for (int nf = 0; nf < 4; ++nf)
#pragma unroll
        for (int reg = 0; reg < 4; ++reg) {
          int m = wm * 64 + mf * 16 + 4 * g + reg;
          int n = wn * 64 + nf * 16 + r;
          netout[(size_t)(t0 + m) * 128 + n] = (hf)d[mf][nf][reg];
        }
  }
}

// ---------------- streaming gather-mean + transpose -------------------------
__global__ __launch_bounds__(256) void k_write(
    const hf* __restrict__ cbuf, const int* __restrict__ start,
    const int* __restrict__ cnt, float* __restrict__ out)
{
  __shared__ float tile[128 * 65];
  const int tid = threadIdx.x;
  const int grp = tid >> 4, q = tid & 15;
  const int g0 = blockIdx.x * 64;        // voxel base, (b<<15)|v0
  for (int vl = grp; vl < 64; vl += 16) {
    const int bv = g0 + vl;
    const int n = cnt[bv];
    const int end = start[bv], beg = end - n;
    float s[8] = {0, 0, 0, 0, 0, 0, 0, 0};
    for (int i = beg; i < end; ++i) {
      union { uint4 u; hf h[8]; } x;
      x.u = *(const uint4*)(cbuf + (size_t)i * 128 + 8 * q);
#pragma unroll
      for (int e = 0; e < 8; ++e) s[e] += (float)x.h[e];
    }
    const float inv = 1.0f / fmaxf((float)n, 1.0f);
#pragma unroll
    for (int e = 0; e < 8; ++e) tile[(8 * q + e) * 65 + vl] = s[e] * inv;
  }
  __syncthreads();
  const int b = g0 >> 15, v0 = g0 & 32767;
  for (int i = tid; i < 8192; i += 256) {
    const int c = i >> 6, vl = i & 63;
    out[(((size_t)(b * 128 + c)) << 15) + v0 + vl] = tile[c * 65 + vl];
  }
}

extern "C" void kernel_launch(void* const* d_in, const int* in_sizes, int n_in,
                              void* d_out, int out_size, void* d_ws, size_t ws_size,
                              hipStream_t stream)
{
  const float* p    = (const float*)d_in[0];
  const float* wpos = (const float*)d_in[1];
  const float* bpos = (const float*)d_in[2];
  const float* w0   = (const float*)d_in[3];
  const float* b0   = (const float*)d_in[4];
  const float* w1   = (const float*)d_in[5];
  const float* b1   = (const float*)d_in[6];
  const float* wsc  = (const float*)d_in[7];
  const float* wc   = (const float*)d_in[8];
  const float* bc   = (const float*)d_in[9];

  char* ws = (char*)d_ws;
  hf*  fr  = (hf*)d_out;  // weight frags; d_out fully overwritten by k_write

  // Layout: idx 1M | netA 64M | netB 64M | cnt .5M | tot | start .5M | svox 1M
  int* idxbuf = (int*)ws;
  hf*  netA   = (hf*)(ws + ((size_t)1u << 20));
  hf*  netB   = (hf*)(ws + ((size_t)65u << 20));
  int* cnt32  = (int*)(ws + ((size_t)129u << 20));
  int* total  = (int*)(ws + ((size_t)129u << 20) + 0x80000);
  int* startb = (int*)(ws + ((size_t)129u << 20) + 0x80400);
  int* svox   = (int*)(ws + ((size_t)129u << 20) + 0x100400);

  k_prep<<<216, 256, 0, stream>>>(wpos, w0, w1, wsc, wc, fr);

  hipMemsetAsync(cnt32, 0, 0x80000 + 0x400, stream);  // cnt + total
  k_idxcnt<<<NPTS / 256, 256, 0, stream>>>(p, idxbuf, cnt32);
  k_scan<<<NVOX / 512, 256, 0, stream>>>(cnt32, startb, total);
  k_fill<<<NPTS / 256, 256, 0, stream>>>(idxbuf, startb, svox);

  k_fused0<<<NPTS / 64, 256, 0, stream>>>(p, fr, bpos,
      fr + OFF_W0, fr + OFF_W1, fr + OFF_WSC, b0, b1, idxbuf, netA);

  hf* bufs[2] = { netA, netB };
  for (int i = 1; i < 4; ++i) {
    k_res<0><<<NPTS / 128, 256, 0, stream>>>(
        bufs[(i + 1) & 1], bufs[i & 1], svox, startb, cnt32,
        fr + OFF_W0 + (size_t)i * 32768, fr + OFF_W1 + (size_t)i * 16384,
        fr + OFF_WSC + (size_t)i * 32768, b0 + i * 128, b1 + i * 128,
        nullptr, nullptr);
  }
  // i=4: B -> A (LAST, fc_c fused)
  k_res<1><<<NPTS / 128, 256, 0, stream>>>(
      netB, netA, svox, startb, cnt32,
      fr + OFF_W0 + (size_t)4 * 32768, fr + OFF_W1 + (size_t)4 * 16384,
      fr + OFF_WSC + (size_t)4 * 32768, b0 + 4 * 128, b1 + 4 * 128,
      fr + OFF_WC, bc);

  k_write<<<NVOX / 64, 256, 0, stream>>>(netA, startb, cnt32, (float*)d_out);
}

// Round 12
// 540.073 us; speedup vs baseline: 3.6444x; 1.0682x over previous
//
#include <hip/hip_runtime.h>

typedef _Float16 hf;
typedef _Float16 hf8 __attribute__((ext_vector_type(8)));
typedef float f32x4 __attribute__((ext_vector_type(4)));

static constexpr int BATCH = 4;
static constexpr int TPTS  = 65536;
static constexpr int NPTS  = BATCH * TPTS;   // 262144
static constexpr int R3    = 32768;
static constexpr int NVOX  = BATCH * R3;     // 131072

// fragment-linear f16 weight buffers (units of hf) inside d_out scratch.
static constexpr int OFF_WPOS = 0;         // K=64(pad 60), N=256: 2048 chunks
static constexpr int OFF_W0   = 16384;     // 5 x (K=256,N=128)
static constexpr int OFF_W1   = 180224;    // 5 x (K=128,N=128)
static constexpr int OFF_WSC  = 262144;    // 5 x (K=256,N=128)
static constexpr int OFF_WC   = 425984;    // K=128,N=128
static constexpr int NCHUNKS  = 55296;

__device__ constexpr int kpat(int g, int j) { return (j & 3) + 4 * g + 16 * (j >> 2); }

#define MFMA16(a, b, c) __builtin_amdgcn_mfma_f32_16x16x32_f16((a), (b), (c), 0, 0, 0)

__device__ inline hf8 relu8(hf8 a) {
#pragma unroll
  for (int i = 0; i < 8; ++i) a[i] = (a[i] > (hf)0) ? a[i] : (hf)0;
  return a;
}
__device__ inline f32x4 splat4(float v) {
  f32x4 r; r[0] = v; r[1] = v; r[2] = v; r[3] = v; return r;
}
__device__ inline hf8 ldfrag(const hf* __restrict__ base, int kc, int nt, int NT, int lane) {
  return *(const hf8*)(base + (((size_t)(kc * NT + nt) * 64 + lane) << 3));
}
// packed f16 max (2 lanes per dword); pure, safe to CSE.
__device__ inline unsigned pkmax(unsigned a, unsigned b) {
  unsigned r;
  asm("v_pk_max_f16 %0, %1, %2" : "=v"(r) : "v"(a), "v"(b));
  return r;
}

// ---------------- weight fragment prep --------------------------------------
__global__ __launch_bounds__(256) void k_prep(
    const float* __restrict__ wpos, const float* __restrict__ w0,
    const float* __restrict__ w1,  const float* __restrict__ wsc,
    const float* __restrict__ wc,  hf* __restrict__ fr)
{
  const int cid = blockIdx.x * 256 + threadIdx.x;
  if (cid >= NCHUNKS) return;
  const float* src; hf* dst; int NT, N, kmax, loc;
  if (cid < 2048) {
    src = wpos; dst = fr + OFF_WPOS; NT = 16; N = 256; kmax = 60; loc = cid;
  } else if (cid < 22528) {
    int l5 = cid - 2048; int i = l5 >> 12; loc = l5 & 4095;
    src = w0 + (size_t)i * 32768; dst = fr + OFF_W0 + (size_t)i * 32768;
    NT = 8; N = 128; kmax = 256;
  } else if (cid < 32768) {
    int l5 = cid - 22528; int i = l5 >> 11; loc = l5 & 2047;
    src = w1 + (size_t)i * 16384; dst = fr + OFF_W1 + (size_t)i * 16384;
    NT = 8; N = 128; kmax = 128;
  } else if (cid < 53248) {
    int l5 = cid - 32768; int i = l5 >> 12; loc = l5 & 4095;
    src = wsc + (size_t)i * 32768; dst = fr + OFF_WSC + (size_t)i * 32768;
    NT = 8; N = 128; kmax = 256;
  } else {
    loc = cid - 53248; src = wc; dst = fr + OFF_WC; NT = 8; N = 128; kmax = 128;
  }
  const int lane = loc & 63;
  const int rest = loc >> 6;
  const int nt = rest % NT, kc = rest / NT;
  const int g = lane >> 4;
  const int n = nt * 16 + (lane & 15);
  union { hf8 h; hf f[8]; } o;
#pragma unroll
  for (int j = 0; j < 8; ++j) {
    int k = kc * 32 + kpat(g, j);
    o.f[j] = (k < kmax) ? (hf)src[(size_t)k * N + n] : (hf)0;
  }
  *(hf8*)(dst + ((size_t)loc << 3)) = o.h;
}

// ---------------- voxel index + count (fused) --------------------------------
__global__ __launch_bounds__(256) void k_idxcnt(
    const float* __restrict__ p, int* __restrict__ idxbuf, int* __restrict__ cnt)
{
  const int t = blockIdx.x * 256 + threadIdx.x;
  const float px = p[(size_t)t * 3 + 0];
  const float py = p[(size_t)t * 3 + 1];
  const float pz = p[(size_t)t * 3 + 2];
  float nx = fminf(fmaxf(px / 1.101f + 0.5f, 0.0f), 0.999f);
  float ny = fminf(fmaxf(py / 1.101f + 0.5f, 0.0f), 0.999f);
  float nz = fminf(fmaxf(pz / 1.101f + 0.5f, 0.0f), 0.999f);
  const int iv = (int)(nx * 32.f) + 32 * (int)(ny * 32.f) + 1024 * (int)(nz * 32.f);
  idxbuf[t] = iv;
  atomicAdd(&cnt[((t >> 16) << 15) | iv], 1);
}

__global__ __launch_bounds__(256) void k_scan(
    const int* __restrict__ cnt, int* __restrict__ start, int* __restrict__ total)
{
  __shared__ int s[256];
  __shared__ int base_s;
  const int tid = threadIdx.x;
  const int v0 = blockIdx.x * 512;
  const int a = cnt[v0 + 2 * tid], b = cnt[v0 + 2 * tid + 1];
  const int sum = a + b;
  s[tid] = sum;
  __syncthreads();
  for (int off = 1; off < 256; off <<= 1) {
    int x = (tid >= off) ? s[tid - off] : 0;
    __syncthreads();
    s[tid] += x;
    __syncthreads();
  }
  if (tid == 255) base_s = atomicAdd(total, s[255]);
  __syncthreads();
  const int excl = base_s + s[tid] - sum;
  start[v0 + 2 * tid]     = excl;
  start[v0 + 2 * tid + 1] = excl + a;
}

// fill: advance start[bv] to END; record sorted slot (spos, in-place over
// idxbuf) and voxel per sorted slot (svox).
__global__ __launch_bounds__(256) void k_fill(
    int* __restrict__ idxbuf, int* __restrict__ start, int* __restrict__ svox)
{
  const int t = blockIdx.x * 256 + threadIdx.x;
  const int bv = ((t >> 16) << 15) | idxbuf[t];
  const int pos = atomicAdd(&start[bv], 1);
  svox[pos] = bv;
  idxbuf[t] = pos;     // idxbuf becomes spos
}

// -------- fused: pos-enc + fc_pos (60->256) + ResnetBlock 0 (64 pts) --------
__global__ __launch_bounds__(256, 4) void k_fused0(
    const float* __restrict__ p, const hf* __restrict__ fr,
    const float* __restrict__ bpos,
    const hf* __restrict__ w0f, const hf* __restrict__ w1f,
    const hf* __restrict__ wscf,
    const float* __restrict__ b0, const float* __restrict__ b1,
    const int* __restrict__ spos, hf* __restrict__ net)
{
  __shared__ __align__(16) hf swX[16384];   // 32 KB: enc (8KB) -> X frags; H aliases
  __shared__ int sp[64];
  const int tid = threadIdx.x;
  const int wv = tid >> 6, lane = tid & 63;
  const int r = lane & 15, g = lane >> 4;
  const int t0 = blockIdx.x * 64;

  if (tid < 64) sp[tid] = spos[t0 + tid];

  // Phase A: cooperative pos-enc (1920 tasks over 256 threads).
  if (tid < 64) {
    const int mt = tid >> 4, rr = tid & 15;
    *(unsigned long long*)(swX + (((mt * 2 + 1) * 64 + 48 + rr) << 3) + 4) = 0ull;
  }
#pragma unroll
  for (int i = 0; i < 8; ++i) {
    const int tau = tid + i * 256;
    if (tau >= 1920) break;
    const int pt = (int)(((unsigned)tau * 34953u) >> 20);   // tau/30
    const int a  = tau - pt * 30;
    const int fi = (a * 11) >> 5;                           // a/3
    const int comp = a - 3 * fi;
    const float pc = p[(size_t)(t0 + pt) * 3 + comp];
    const float ang = (float)(1 << fi) * 3.14159274101257324f * pc;
    const float sv = __sinf(ang), cv = __cosf(ang);
    const int mt = pt >> 4, rr = pt & 15;
    const int ks = 6 * fi + comp;
    {
      const int kc = ks >> 5, kk = ks & 31, gg = (kk >> 2) & 3;
      const int e = (kk & 3) + 4 * (kk >> 4);
      swX[(((mt * 2 + kc) * 64 + gg * 16 + rr) << 3) + e] = (hf)sv;
    }
    {
      const int kco = ks + 3;
      const int kc = kco >> 5, kk = kco & 31, gg = (kk >> 2) & 3;
      const int e = (kk & 3) + 4 * (kk >> 4);
      swX[(((mt * 2 + kc) * 64 + gg * 16 + rr) << 3) + e] = (hf)cv;
    }
  }
  __syncthreads();

  // fc_pos via MFMA, A-fragments from LDS
  f32x4 acc[4][4];
#pragma unroll
  for (int nf = 0; nf < 4; ++nf) {
    float bv = bpos[wv * 64 + nf * 16 + r];
#pragma unroll
    for (int mf = 0; mf < 4; ++mf) acc[mf][nf] = splat4(bv);
  }
#pragma unroll
  for (int kc = 0; kc < 2; ++kc) {
    hf8 a[4];
#pragma unroll
    for (int mf = 0; mf < 4; ++mf)
      a[mf] = *(const hf8*)(swX + (((mf * 2 + kc) * 64 + lane) << 3));
#pragma unroll
    for (int nf = 0; nf < 4; ++nf) {
      hf8 b = ldfrag(fr + OFF_WPOS, kc, wv * 4 + nf, 16, lane);
#pragma unroll
      for (int mf = 0; mf < 4; ++mf) acc[mf][nf] = MFMA16(a[mf], b, acc[mf][nf]);
    }
  }
  __syncthreads();   // enc region dead; X-store below overwrites it

  // X -> frag-linear LDS, swizzled slot
#pragma unroll
  for (int mf = 0; mf < 4; ++mf)
#pragma unroll
    for (int nf = 0; nf < 4; ++nf)
#pragma unroll
      for (int reg = 0; reg < 4; ++reg) {
        int rr = 4 * g + reg;
        int c  = wv * 64 + nf * 16 + r;
        int kc = c >> 5;
        int kk = c & 31;
        int gg = (kk >> 2) & 3;
        int e  = (kk & 3) + 4 * (kk >> 4);
        int slot = gg * 16 + ((rr + gg) & 15);
        swX[(((size_t)(mf * 8 + kc) * 64 + slot) << 3) + e] = (hf)acc[mf][nf][reg];
      }
  __syncthreads();

  const int wm = wv >> 1, wn = wv & 1;
  const int lidx = g * 16 + ((r + g) & 15);

  f32x4 h[2][4], d[2][4];
#pragma unroll
  for (int nf = 0; nf < 4; ++nf) {
    const int n = wn * 64 + nf * 16 + r;
    const float bh = b0[n], bd = b1[n];
#pragma unroll
    for (int mf = 0; mf < 2; ++mf) { h[mf][nf] = splat4(bh); d[mf][nf] = splat4(bd); }
  }
#pragma unroll 2
  for (int kc = 0; kc < 8; ++kc) {
    hf8 a[2], ar[2];
#pragma unroll
    for (int mf = 0; mf < 2; ++mf) {
      a[mf] = *(const hf8*)(swX + (((size_t)((wm * 2 + mf) * 8 + kc) * 64 + lidx) << 3));
      ar[mf] = relu8(a[mf]);
    }
#pragma unroll
    for (int nf = 0; nf < 4; ++nf) {
      hf8 bw0 = ldfrag(w0f, kc, wn * 4 + nf, 8, lane);
      hf8 bws = ldfrag(wscf, kc, wn * 4 + nf, 8, lane);
#pragma unroll
      for (int mf = 0; mf < 2; ++mf) {
        h[mf][nf] = MFMA16(ar[mf], bw0, h[mf][nf]);
        d[mf][nf] = MFMA16(a[mf],  bws, d[mf][nf]);
      }
    }
  }
  __syncthreads();

#pragma unroll
  for (int mf = 0; mf < 2; ++mf)
#pragma unroll
    for (int nf = 0; nf < 4; ++nf)
#pragma unroll
      for (int reg = 0; reg < 4; ++reg) {
        int m = wm * 32 + mf * 16 + 4 * g + reg;
        int k = wn * 64 + nf * 16 + r;
        float hv = fmaxf(h[mf][nf][reg], 0.f);
        int mt = m >> 4, rr = m & 15;
        int kc = k >> 5, kk = k & 31;
        int gg = (kk >> 2) & 3;
        int e = (kk & 3) + 4 * (kk >> 4);
        int slot = gg * 16 + ((rr + gg) & 15);
        swX[(((size_t)(mt * 4 + kc) * 64 + slot) << 3) + e] = (hf)hv;
      }
  __syncthreads();

#pragma unroll
  for (int kc = 0; kc < 4; ++kc) {
    hf8 a[2];
#pragma unroll
    for (int mf = 0; mf < 2; ++mf)
      a[mf] = *(const hf8*)(swX + (((size_t)((wm * 2 + mf) * 4 + kc) * 64 + lidx) << 3));
#pragma unroll
    for (int nf = 0; nf < 4; ++nf) {
      hf8 bw1 = ldfrag(w1f, kc, wn * 4 + nf, 8, lane);
#pragma unroll
      for (int mf = 0; mf < 2; ++mf) d[mf][nf] = MFMA16(a[mf], bw1, d[mf][nf]);
    }
  }

#pragma unroll
  for (int mf = 0; mf < 2; ++mf)
#pragma unroll
    for (int nf = 0; nf < 4; ++nf)
#pragma unroll
      for (int reg = 0; reg < 4; ++reg) {
        int m = wm * 32 + mf * 16 + 4 * g + reg;
        int n = wn * 64 + nf * 16 + r;
        net[(size_t)sp[m] * 128 + n] = (hf)d[mf][nf][reg];
      }
}

// ---- ResnetBlockFC for 128 sorted points via MFMA (64KB LDS, 2 blk/CU). ----
// Pooled X-half computed in-kernel via CSR segment walks over netin
// (ping-pong netin != netout). Walk uses v_pk_max_f16 (no f32 round-trip)
// and a 1-deep load prefetch so L2 latency overlaps the max ops.
// LAST=1: fc_c fused at the tail.
template <int LAST>
__global__ __launch_bounds__(256, 2) void k_res(
    const hf* __restrict__ netin, hf* __restrict__ netout,
    const int* __restrict__ svox,
    const int* __restrict__ startb, const int* __restrict__ cnt,
    const hf* __restrict__ w0f, const hf* __restrict__ w1f,
    const hf* __restrict__ wscf,
    const float* __restrict__ b0, const float* __restrict__ b1,
    const hf* __restrict__ wcf, const float* __restrict__ bc)
{
  __shared__ __align__(16) hf swX[32768];   // 64 KB: X frags; H (32KB) aliases
  const int tid = threadIdx.x;
  const int wv = tid >> 6, lane = tid & 63;
  const int r = lane & 15, g = lane >> 4;
  const int wm = wv >> 1, wn = wv & 1;
  const int t0 = blockIdx.x * 128;
  const int lidx = g * 16 + ((r + g) & 15);

  // lower half: net channels 0-127 of own rows
  for (int cc = tid; cc < 2048; cc += 256) {
    const int cl = cc & 63;
    const int kc = (cc >> 6) & 3;      // 0..3
    const int mt = cc >> 8;            // 0..7
    const int rr = cl & 15, gg = cl >> 4;
    const int t = t0 + mt * 16 + rr;
    const int c1 = kc * 32 + 4 * gg;
    union { hf8 h; uint2 u2[2]; } x;
    const hf* srcp = netin + (size_t)t * 128 + c1;
    x.u2[0] = *(const uint2*)(srcp);
    x.u2[1] = *(const uint2*)(srcp + 16);
    const int slot = gg * 16 + ((rr + gg) & 15);
    *(hf8*)(swX + (((size_t)((mt * 8 + kc) * 64 + slot)) << 3)) = x.h;
  }
  // upper half: pooled values via CSR segment walks (group = 8 rows x 8 ch).
  {
    const int grp = tid >> 4, q = tid & 15;
    const int rbase = t0 + grp * 8;
    int vprev = -1;
    union { unsigned u[4]; hf f[8]; } mm;
    mm.u[0] = mm.u[1] = mm.u[2] = mm.u[3] = 0xFC00FC00u;  // (-inf, -inf)
    for (int rloc = 0; rloc < 8; ++rloc) {
      const int t = rbase + rloc;
      const int v = svox[t];
      if (v != vprev) {
        vprev = v;
        const int end = startb[v];
        const int beg = end - cnt[v];
        mm.u[0] = mm.u[1] = mm.u[2] = mm.u[3] = 0xFC00FC00u;
        uint4 cur = *(const uint4*)(netin + (size_t)beg * 128 + 8 * q);
        for (int j = beg + 1; j < end; ++j) {
          uint4 nxt = *(const uint4*)(netin + (size_t)j * 128 + 8 * q);
          mm.u[0] = pkmax(mm.u[0], cur.x);
          mm.u[1] = pkmax(mm.u[1], cur.y);
          mm.u[2] = pkmax(mm.u[2], cur.z);
          mm.u[3] = pkmax(mm.u[3], cur.w);
          cur = nxt;
        }
        mm.u[0] = pkmax(mm.u[0], cur.x);
        mm.u[1] = pkmax(mm.u[1], cur.y);
        mm.u[2] = pkmax(mm.u[2], cur.z);
        mm.u[3] = pkmax(mm.u[3], cur.w);
      }
      const int mt = (t - t0) >> 4, rr = (t - t0) & 15;
#pragma unroll
      for (int i = 0; i < 8; ++i) {
        const int c = 128 + 8 * q + i;
        const int kc = c >> 5;                    // 4..7
        const int kk = c & 31;
        const int gg = (kk >> 2) & 3;
        const int e = (kk & 3) + 4 * (kk >> 4);
        const int slot = gg * 16 + ((rr + gg) & 15);
        swX[(((size_t)((mt * 8 + kc) * 64 + slot)) << 3) + e] = mm.f[i];
      }
    }
  }
  __syncthreads();

  f32x4 h[4][4], d[4][4];
#pragma unroll
  for (int nf = 0; nf < 4; ++nf) {
    const int n = wn * 64 + nf * 16 + r;
    const float bh = b0[n], bd = b1[n];
#pragma unroll
    for (int mf = 0; mf < 4; ++mf) { h[mf][nf] = splat4(bh); d[mf][nf] = splat4(bd); }
  }
#pragma unroll 2
  for (int kc = 0; kc < 8; ++kc) {
    hf8 a[4], ar[4];
#pragma unroll
    for (int mf = 0; mf < 4; ++mf) {
      a[mf] = *(const hf8*)(swX + (((size_t)((wm * 4 + mf) * 8 + kc) * 64 + lidx) << 3));
      ar[mf] = relu8(a[mf]);
    }
#pragma unroll
    for (int nf = 0; nf < 4; ++nf) {
      hf8 bw0 = ldfrag(w0f, kc, wn * 4 + nf, 8, lane);
      hf8 bws = ldfrag(wscf, kc, wn * 4 + nf, 8, lane);
#pragma unroll
      for (int mf = 0; mf < 4; ++mf) {
        h[mf][nf] = MFMA16(ar[mf], bw0, h[mf][nf]);
        d[mf][nf] = MFMA16(a[mf],  bws, d[mf][nf]);
      }
    }
  }
  __syncthreads();

  // H = relu(h) -> swX[0..16384), swizzled
#pragma unroll
  for (int mf = 0; mf < 4; ++mf)
#pragma unroll
    for (int nf = 0; nf < 4; ++nf)
#pragma unroll
      for (int reg = 0; reg < 4; ++reg) {
        int m = wm * 64 + mf * 16 + 4 * g + reg;
        int k = wn * 64 + nf * 16 + r;
        float hv = fmaxf(h[mf][nf][reg], 0.f);
        int mt = m >> 4, rr = m & 15;
        int kc = k >> 5, kk = k & 31;
        int gg = (kk >> 2) & 3;
        int e = (kk & 3) + 4 * (kk >> 4);
        int slot = gg * 16 + ((rr + gg) & 15);
        swX[(((size_t)(mt * 4 + kc) * 64 + slot) << 3) + e] = (hf)hv;
      }
  __syncthreads();

#pragma unroll
  for (int kc = 0; kc < 4; ++kc) {
    hf8 a[4];
#pragma unroll
    for (int mf = 0; mf < 4; ++mf)
      a[mf] = *(const hf8*)(swX + (((size_t)((wm * 4 + mf) * 4 + kc) * 64 + lidx) << 3));
#pragma unroll
    for (int nf = 0; nf < 4; ++nf) {
      hf8 bw1 = ldfrag(w1f, kc, wn * 4 + nf, 8, lane);
#pragma unroll
      for (int mf = 0; mf < 4; ++mf) d[mf][nf] = MFMA16(a[mf], bw1, d[mf][nf]);
    }
  }

  if (LAST) {
    __syncthreads();
#pragma unroll
    for (int mf = 0; mf < 4; ++mf)
#pragma unroll
      for (int nf = 0; nf < 4; ++nf)
#pragma unroll
        for (int reg = 0; reg < 4; ++reg) {
          int m = wm * 64 + mf * 16 + 4 * g + reg;
          int k = wn * 64 + nf * 16 + r;
          int mt = m >> 4, rr = m & 15;
          int kc = k >> 5, kk = k & 31;
          int gg = (kk >> 2) & 3;
          int e = (kk & 3) + 4 * (kk >> 4);
          int slot = gg * 16 + ((rr + gg) & 15);
          swX[(((size_t)(mt * 4 + kc) * 64 + slot) << 3) + e] = (hf)d[mf][nf][reg];
        }
    __syncthreads();

    f32x4 c2[4][4];
#pragma unroll
    for (int nf = 0; nf < 4; ++nf) {
      float bv = bc[wn * 64 + nf * 16 + r];
#pragma unroll
      for (int mf = 0; mf < 4; ++mf) c2[mf][nf] = splat4(bv);
    }
#pragma unroll
    for (int kc = 0; kc < 4; ++kc) {
      hf8 a[4];
#pragma unroll
      for (int mf = 0; mf < 4; ++mf)
        a[mf] = *(const hf8*)(swX + (((size_t)((wm * 4 + mf) * 4 + kc) * 64 + lidx) << 3));
#pragma unroll
      for (int nf = 0; nf < 4; ++nf) {
        hf8 bw = ldfrag(wcf, kc, wn * 4 + nf, 8, lane);
#pragma unroll
        for (int mf = 0; mf < 4; ++mf) c2[mf][nf] = MFMA16(a[mf], bw, c2[mf][nf]);
      }
    }
#pragma unroll
    for (int mf = 0; mf < 4; ++mf)
#pragma unroll
      for (int nf = 0; nf < 4; ++nf)
#pragma unroll
        for (int reg = 0; reg < 4; ++reg) {
          int m = wm * 64 + mf * 16 + 4 * g + reg;
          int n = wn * 64 + nf * 16 + r;
          netout[(size_t)(t0 + m) * 128 + n] = (hf)c2[mf][nf][reg];
        }
  } else {
#pragma unroll
    for (int mf = 0; mf < 4; ++mf)
#pragma unroll
      for (int nf = 0; nf < 4; ++nf)
#pragma unroll
        for (int reg = 0; reg < 4; ++reg) {
          int m = wm * 64 + mf * 16 + 4 * g + reg;
          int n = wn * 64 + nf * 16 + r;
          netout[(size_t)(t0 + m) * 128 + n] = (hf)d[mf][nf][reg];
        }
  }
}

// ---------------- streaming gather-mean + transpose -------------------------
__global__ __launch_bounds__(256) void k_write(
    const hf* __restrict__ cbuf, const int* __restrict__ start,
    const int* __restrict__ cnt, float* __restrict__ out)
{
  __shared__ float tile[128 * 65];
  const int tid = threadIdx.x;
  const int grp = tid >> 4, q = tid & 15;
  const int g0 = blockIdx.x * 64;        // voxel base, (b<<15)|v0
  for (int vl = grp; vl < 64; vl += 16) {
    const int bv = g0 + vl;
    const int n = cnt[bv];
    const int end = start[bv], beg = end - n;
    float s[8] = {0, 0, 0, 0, 0, 0, 0, 0};
    for (int i = beg; i < end; ++i) {
      union { uint4 u; hf h[8]; } x;
      x.u = *(const uint4*)(cbuf + (size_t)i * 128 + 8 * q);
#pragma unroll
      for (int e = 0; e < 8; ++e) s[e] += (float)x.h[e];
    }
    const float inv = 1.0f / fmaxf((float)n, 1.0f);
#pragma unroll
    for (int e = 0; e < 8; ++e) tile[(8 * q + e) * 65 + vl] = s[e] * inv;
  }
  __syncthreads();
  const int b = g0 >> 15, v0 = g0 & 32767;
  for (int i = tid; i < 8192; i += 256) {
    const int c = i >> 6, vl = i & 63;
    out[(((size_t)(b * 128 + c)) << 15) + v0 + vl] = tile[c * 65 + vl];
  }
}

extern "C" void kernel_launch(void* const* d_in, const int* in_sizes, int n_in,
                              void* d_out, int out_size, void* d_ws, size_t ws_size,
                              hipStream_t stream)
{
  const float* p    = (const float*)d_in[0];
  const float* wpos = (const float*)d_in[1];
  const float* bpos = (const float*)d_in[2];
  const float* w0   = (const float*)d_in[3];
  const float* b0   = (const float*)d_in[4];
  const float* w1   = (const float*)d_in[5];
  const float* b1   = (const float*)d_in[6];
  const float* wsc  = (const float*)d_in[7];
  const float* wc   = (const float*)d_in[8];
  const float* bc   = (const float*)d_in[9];

  char* ws = (char*)d_ws;
  hf*  fr  = (hf*)d_out;  // weight frags; d_out fully overwritten by k_write

  // Layout: idx 1M | netA 64M | netB 64M | cnt .5M | tot | start .5M | svox 1M
  int* idxbuf = (int*)ws;
  hf*  netA   = (hf*)(ws + ((size_t)1u << 20));
  hf*  netB   = (hf*)(ws + ((size_t)65u << 20));
  int* cnt32  = (int*)(ws + ((size_t)129u << 20));
  int* total  = (int*)(ws + ((size_t)129u << 20) + 0x80000);
  int* startb = (int*)(ws + ((size_t)129u << 20) + 0x80400);
  int* svox   = (int*)(ws + ((size_t)129u << 20) + 0x100400);

  k_prep<<<216, 256, 0, stream>>>(wpos, w0, w1, wsc, wc, fr);

  hipMemsetAsync(cnt32, 0, 0x80000 + 0x400, stream);  // cnt + total
  k_idxcnt<<<NPTS / 256, 256, 0, stream>>>(p, idxbuf, cnt32);
  k_scan<<<NVOX / 512, 256, 0, stream>>>(cnt32, startb, total);
  k_fill<<<NPTS / 256, 256, 0, stream>>>(idxbuf, startb, svox);

  k_fused0<<<NPTS / 64, 256, 0, stream>>>(p, fr, bpos,
      fr + OFF_W0, fr + OFF_W1, fr + OFF_WSC, b0, b1, idxbuf, netA);

  hf* bufs[2] = { netA, netB };
  for (int i = 1; i < 4; ++i) {
    k_res<0><<<NPTS / 128, 256, 0, stream>>>(
        bufs[(i + 1) & 1], bufs[i & 1], svox, startb, cnt32,
        fr + OFF_W0 + (size_t)i * 32768, fr + OFF_W1 + (size_t)i * 16384,
        fr + OFF_WSC + (size_t)i * 32768, b0 + i * 128, b1 + i * 128,
        nullptr, nullptr);
  }
  // i=4: B -> A (LAST, fc_c fused)
  k_res<1><<<NPTS / 128, 256, 0, stream>>>(
      netB, netA, svox, startb, cnt32,
      fr + OFF_W0 + (size_t)4 * 32768, fr + OFF_W1 + (size_t)4 * 16384,
      fr + OFF_WSC + (size_t)4 * 32768, b0 + 4 * 128, b1 + 4 * 128,
      fr + OFF_WC, bc);

  k_write<<<NVOX / 64, 256, 0, stream>>>(netA, startb, cnt32, (float*)d_out);
}